// Round 1
// baseline (82.678 us; speedup 1.0000x reference)
//
#include <hip/hip_runtime.h>
#include <hip/hip_bf16.h>

// Problem constants (T=512, B=32, D=128, 9 table rows after clipping)
#define TBPAIRS 16384
#define DEMB    128
#define NRROWS  9
#define BP      64    // pairs per block in the GEMM kernel

using short8 = __attribute__((ext_vector_type(8))) short;
using f32x4  = __attribute__((ext_vector_type(4))) float;

// fp32 -> bf16, round-to-nearest-even (bit trick)
__device__ __forceinline__ unsigned short f2bf(float f) {
    unsigned u = __float_as_uint(f);
    u = u + 0x7FFFu + ((u >> 16) & 1u);
    return (unsigned short)(u >> 16);
}

// ---------------------------------------------------------------------------
// Kernel 1: pack table (9 x 128 x 128 fp32, layout M[r][d][e]) into bf16
// B-fragment order for mfma_f32_16x16x32_bf16:
//   frag element (r, nt, ks, lane, j) = M[r][d = ks*32 + (lane>>4)*8 + j]
//                                        [e = nt*16 + (lane&15)]
// stored at uint4 index r*2048 + nt*256 + ks*64 + lane  (16 B per lane).
// Total: 9 * 32 KB = 288 KB in d_ws.
// ---------------------------------------------------------------------------
__global__ __launch_bounds__(256) void pack_table_kernel(
    const float* __restrict__ table, uint4* __restrict__ bpack) {
    const int r = blockIdx.x;
    const float* M = table + r * DEMB * DEMB;
    for (int idx = threadIdx.x; idx < 2048; idx += 256) {
        const int lane = idx & 63;
        const int ks   = (idx >> 6) & 3;
        const int nt   = idx >> 8;
        const int e    = nt * 16 + (lane & 15);
        const int d0   = ks * 32 + (lane >> 4) * 8;
        union { unsigned short us[8]; uint4 v; } u;
#pragma unroll
        for (int j = 0; j < 8; ++j)
            u.us[j] = f2bf(M[(d0 + j) * DEMB + e]);
        bpack[r * 2048 + idx] = u.v;
    }
}

// ---------------------------------------------------------------------------
// Kernel 2: per-block bucketize 64 pairs by r, then MFMA GEMM per bucket.
// C[m=pair][n=e] = sum_d A[m][d] * B[d][n],  A = x rows (bf16), B = packed M.
// ---------------------------------------------------------------------------
__global__ __launch_bounds__(256) void transfer_kernel(
    const int*   __restrict__ positions,
    const float* __restrict__ x,
    const uint4* __restrict__ bpack,
    float*       __restrict__ out) {

    __shared__ unsigned char list[NRROWS][BP];
    __shared__ int cnt[NRROWS];
    __shared__ unsigned char tile_r[16];
    __shared__ unsigned char tile_s[16];
    __shared__ int ntiles;

    const int tid   = threadIdx.x;
    const int pair0 = blockIdx.x * BP;

    if (tid < NRROWS) cnt[tid] = 0;
    __syncthreads();

    if (tid < BP) {
        int p = positions[pair0 + tid];
        int r = (p < 8) ? p : 8;
        int rank = atomicAdd(&cnt[r], 1);
        list[r][rank] = (unsigned char)tid;
    }
    __syncthreads();

    if (tid == 0) {
        int nt = 0;
        for (int r = 0; r < NRROWS; ++r)
            for (int s = 0; s < cnt[r]; s += 16) {
                tile_r[nt] = (unsigned char)r;
                tile_s[nt] = (unsigned char)s;
                ++nt;
            }
        ntiles = nt;
    }
    __syncthreads();

    const int wave = tid >> 6;
    const int lane = tid & 63;
    const int m16  = lane & 15;   // m (pair-in-tile) for A; n (col) for C/D
    const int quad = lane >> 4;   // k-chunk selector
    const int nt_total = ntiles;

    for (int t = wave; t < nt_total; t += 4) {
        const int r = tile_r[t];
        const int s = tile_s[t];
        const int c = cnt[r];

        // ---- A fragments: x rows for this tile's 16 pairs, bf16-converted.
        // Lane layout: A[m = lane&15][k = ks*32 + (lane>>4)*8 + j]
        const int slotA = (s + m16 < c) ? list[r][s + m16] : list[r][s];
        const float* xrow = x + (size_t)(pair0 + slotA) * DEMB;
        short8 a[4];
#pragma unroll
        for (int ks = 0; ks < 4; ++ks) {
            const float4* s4 = (const float4*)(xrow + ks * 32 + quad * 8);
            float4 f0 = s4[0];
            float4 f1 = s4[1];
            union { unsigned short us[8]; short8 s8; } ua;
            ua.us[0] = f2bf(f0.x); ua.us[1] = f2bf(f0.y);
            ua.us[2] = f2bf(f0.z); ua.us[3] = f2bf(f0.w);
            ua.us[4] = f2bf(f1.x); ua.us[5] = f2bf(f1.y);
            ua.us[6] = f2bf(f1.z); ua.us[7] = f2bf(f1.w);
            a[ks] = ua.s8;
        }

        // ---- output rows this lane is responsible for (C/D layout:
        // col = lane&15, row = (lane>>4)*4 + i)
        int  prow[4];
        bool pval[4];
#pragma unroll
        for (int i = 0; i < 4; ++i) {
            const int m = quad * 4 + i;
            pval[i] = (s + m) < c;
            prow[i] = pval[i] ? (pair0 + list[r][s + m]) : 0;
        }

        const uint4* bp = bpack + r * 2048 + lane;
#pragma unroll
        for (int nt = 0; nt < 8; ++nt) {
            f32x4 acc = {0.f, 0.f, 0.f, 0.f};
#pragma unroll
            for (int ks = 0; ks < 4; ++ks) {
                union { uint4 v; short8 s8; } ub;
                ub.v = bp[(nt * 4 + ks) * 64];
                acc = __builtin_amdgcn_mfma_f32_16x16x32_bf16(a[ks], ub.s8, acc, 0, 0, 0);
            }
            const int col = nt * 16 + m16;
#pragma unroll
            for (int i = 0; i < 4; ++i)
                if (pval[i]) out[(size_t)prow[i] * DEMB + col] = acc[i];
        }
    }
}

extern "C" void kernel_launch(void* const* d_in, const int* in_sizes, int n_in,
                              void* d_out, int out_size, void* d_ws, size_t ws_size,
                              hipStream_t stream) {
    const int*   positions = (const int*)d_in[0];   // (T*B,) clipped to 0..8 in-kernel
    const float* outputs   = (const float*)d_in[1]; // (T*B, 128) fp32
    const float* table     = (const float*)d_in[2]; // (9, 128, 128) fp32
    float* out = (float*)d_out;                     // (T*B, 128) fp32
    uint4* bpack = (uint4*)d_ws;                    // 288 KB packed bf16 table

    hipLaunchKernelGGL(pack_table_kernel, dim3(NRROWS), dim3(256), 0, stream,
                       table, bpack);
    hipLaunchKernelGGL(transfer_kernel, dim3(TBPAIRS / BP), dim3(256), 0, stream,
                       positions, outputs, bpack, out);
}

// Round 2
// 80.735 us; speedup vs baseline: 1.0241x; 1.0241x over previous
//
#include <hip/hip_runtime.h>
#include <hip/hip_bf16.h>

// Problem constants (T=512, B=32, D=128, 9 table rows after clipping).
// positions uniform 0..15 -> ~50% clip to bucket 8.
#define TBPAIRS 16384
#define DEMB    128
#define NR      9
#define CAP     16384              // per-bucket perm capacity (worst case)
#define CHUNK   64                 // pairs per work item in kernel 2
#define NCHUNK  (TBPAIRS / CHUNK)  // 256 chunks per bucket
#define NVIRT   (NR * NCHUNK)      // 2304 virtual work items
#define GRID2   512                // 2 blocks/CU

#define BPACK_U4    (NR * 2048)          // 18432 uint4 = 288 KB
#define BPACK_BYTES (BPACK_U4 * 16)      // 294912

using short8 = __attribute__((ext_vector_type(8))) short;
using f32x4  = __attribute__((ext_vector_type(4))) float;

// fp32 -> bf16 round-to-nearest-even
__device__ __forceinline__ unsigned short f2bf(float f) {
    unsigned u = __float_as_uint(f);
    u = u + 0x7FFFu + ((u >> 16) & 1u);
    return (unsigned short)(u >> 16);
}

// ---------------------------------------------------------------------------
// Kernel 1: blocks 0..63  -> global bucketize (perm + gcnt)
//           blocks 64..99 -> pack table row r=(bid-64)>>2, segment (bid-64)&3
// B-fragment order for mfma_f32_16x16x32_bf16 (same as R1, verified correct):
//   uint4 index r*2048 + nt*256 + ks*64 + lane holds
//   M[r][d = ks*32 + (lane>>4)*8 + j][e = nt*16 + (lane&15)], j=0..7
// ---------------------------------------------------------------------------
__global__ __launch_bounds__(256) void prep_kernel(
    const int*   __restrict__ positions,
    const float* __restrict__ table,
    uint4* __restrict__ bpack,
    int*   __restrict__ gcnt,   // 9 counters, pre-zeroed by memset node
    int*   __restrict__ perm) {

    const int bid = blockIdx.x;
    const int tid = threadIdx.x;

    if (bid < 64) {
        // ---- bucketize 256 pairs
        __shared__ int lcnt[NR];
        __shared__ int lbase[NR];
        if (tid < NR) lcnt[tid] = 0;
        __syncthreads();
        const int pair = bid * 256 + tid;
        const int p = positions[pair];
        const int r = (p < 8) ? p : 8;
        const int rank = atomicAdd(&lcnt[r], 1);
        __syncthreads();
        if (tid < NR) lbase[tid] = atomicAdd(&gcnt[tid], lcnt[tid]);
        __syncthreads();
        perm[r * CAP + lbase[r] + rank] = pair;
    } else {
        // ---- pack one quarter of one table row
        const int pid = bid - 64;
        const int r   = pid >> 2;
        const int seg = pid & 3;
        const float* M = table + r * DEMB * DEMB;
#pragma unroll
        for (int k = 0; k < 2; ++k) {
            const int idx  = seg * 512 + k * 256 + tid;  // 0..2047 within row
            const int lane = idx & 63;
            const int ks   = (idx >> 6) & 3;
            const int nt   = idx >> 8;
            const int e    = nt * 16 + (lane & 15);
            const int d0   = ks * 32 + (lane >> 4) * 8;
            union { unsigned short us[8]; uint4 v; } u;
#pragma unroll
            for (int j = 0; j < 8; ++j)
                u.us[j] = f2bf(M[(d0 + j) * DEMB + e]);
            bpack[r * 2048 + idx] = u.v;
        }
    }
}

// ---------------------------------------------------------------------------
// Kernel 2: persistent blocks over virtual items v = (r = v%9, chunk = v/9).
// Chunk = 64 pairs of ONE bucket -> 4 full 16-pair MFMA tiles (1 per wave).
// ---------------------------------------------------------------------------
__global__ __launch_bounds__(256) void transfer_kernel(
    const float* __restrict__ x,
    const uint4* __restrict__ bpack,
    const int*   __restrict__ gcnt,
    const int*   __restrict__ perm,
    float*       __restrict__ out) {

    const int tid  = threadIdx.x;
    const int wave = tid >> 6;
    const int lane = tid & 63;
    const int m16  = lane & 15;   // m (pair-in-tile) for A; n (col) for C/D
    const int quad = lane >> 4;

    for (int v = blockIdx.x; v < NVIRT; v += GRID2) {
        const int r     = v % NR;
        const int chunk = v / NR;
        const int c     = gcnt[r];
        const int base  = chunk * CHUNK;
        if (base >= c) continue;          // dead item: one L2-hot load
        const int tb = base + wave * 16;  // this wave's tile
        if (tb >= c) continue;            // partial chunk tail
        const int nm = c - tb;            // valid pairs in tile (1..16)

        const int* pr = perm + r * CAP + tb;

        // ---- A fragments: A[m = lane&15][k = ks*32 + quad*8 + j]
        const int slotA = pr[(m16 < nm) ? m16 : 0];
        const float* xrow = x + (size_t)slotA * DEMB;
        short8 a[4];
#pragma unroll
        for (int ks = 0; ks < 4; ++ks) {
            const float4* s4 = (const float4*)(xrow + ks * 32 + quad * 8);
            float4 f0 = s4[0];
            float4 f1 = s4[1];
            union { unsigned short us[8]; short8 s8; } ua;
            ua.us[0] = f2bf(f0.x); ua.us[1] = f2bf(f0.y);
            ua.us[2] = f2bf(f0.z); ua.us[3] = f2bf(f0.w);
            ua.us[4] = f2bf(f1.x); ua.us[5] = f2bf(f1.y);
            ua.us[6] = f2bf(f1.z); ua.us[7] = f2bf(f1.w);
            a[ks] = ua.s8;
        }

        // ---- C/D rows: col = lane&15, row m = quad*4 + i
        int  prow[4];
        bool pval[4];
#pragma unroll
        for (int i = 0; i < 4; ++i) {
            const int m = quad * 4 + i;
            pval[i] = m < nm;
            prow[i] = pval[i] ? pr[m] : 0;
        }

        const uint4* bp = bpack + r * 2048 + lane;
#pragma unroll 2
        for (int nt = 0; nt < 8; ++nt) {
            f32x4 acc = {0.f, 0.f, 0.f, 0.f};
#pragma unroll
            for (int ks = 0; ks < 4; ++ks) {
                union { uint4 v4; short8 s8; } ub;
                ub.v4 = bp[(nt * 4 + ks) * 64];
                acc = __builtin_amdgcn_mfma_f32_16x16x32_bf16(a[ks], ub.s8, acc, 0, 0, 0);
            }
            const int col = nt * 16 + m16;
#pragma unroll
            for (int i = 0; i < 4; ++i)
                if (pval[i]) out[(size_t)prow[i] * DEMB + col] = acc[i];
        }
    }
}

extern "C" void kernel_launch(void* const* d_in, const int* in_sizes, int n_in,
                              void* d_out, int out_size, void* d_ws, size_t ws_size,
                              hipStream_t stream) {
    const int*   positions = (const int*)d_in[0];   // (16384,) int32
    const float* outputs   = (const float*)d_in[1]; // (16384, 128) fp32
    const float* table     = (const float*)d_in[2]; // (9, 128, 128) fp32
    float* out = (float*)d_out;                     // (16384, 128) fp32

    uint4* bpack = (uint4*)d_ws;                            // 288 KB
    int*   gcnt  = (int*)((char*)d_ws + BPACK_BYTES);       // 9 ints (pad to 64 B)
    int*   perm  = (int*)((char*)d_ws + BPACK_BYTES + 64);  // 9*16384 ints

    // zero the bucket counters (graph-capturable memset node)
    hipMemsetAsync((void*)gcnt, 0, 64, stream);

    hipLaunchKernelGGL(prep_kernel, dim3(100), dim3(256), 0, stream,
                       positions, table, bpack, gcnt, perm);
    hipLaunchKernelGGL(transfer_kernel, dim3(GRID2), dim3(256), 0, stream,
                       outputs, bpack, gcnt, perm, out);
}